// Round 12
// baseline (1444.922 us; speedup 1.0000x reference)
//
#include <hip/hip_runtime.h>

#define T_STEPS 2048
#define TOTAL   2080   // T_STEPS + 32 (deepest lag)

typedef float f2 __attribute__((ext_vector_type(2)));
typedef _Float16 h2 __attribute__((ext_vector_type(2)));

__device__ __forceinline__ float fast_rcp(float x) { return __builtin_amdgcn_rcpf(x); }

__device__ __forceinline__ float sig_f(float x) {
    return fast_rcp(1.0f + __expf(-x));
}
__device__ __forceinline__ float tanh_f(float x) {
    float e = __expf(-2.0f * x);
    return fmaf(2.0f, fast_rcp(1.0f + e), -1.0f);
}
__device__ __forceinline__ float gate_act(float x, float zm, float sm, float sa) {
    float e = __expf(-x * zm);
    return fmaf(fast_rcp(1.0f + e), sm, sa);
}

// f16 dot2 with f32 accumulate
#if __has_builtin(__builtin_amdgcn_fdot2)
#define FDOT2(a, b, c) __builtin_amdgcn_fdot2((a), (b), (c), false)
#else
__device__ __forceinline__ float FDOT2(h2 a, h2 b, float c) {
    return fmaf((float)a.x, (float)b.x, fmaf((float)a.y, (float)b.y, c));
}
#endif

// Drain ONLY lgkmcnt (LDS) before barrier — never vmcnt (R7 win).
#define LDS_BARRIER() asm volatile("s_waitcnt lgkmcnt(0)\n\ts_barrier" ::: "memory")

#define DPP_BCAST0 0x00
#define DPP_BCAST1 0x55
#define DPP_BCAST2 0xAA
#define DPP_BCAST3 0xFF
#define DPP_PAIR   0xF5    // quad_perm [1,1,3,3]: even lane gets odd partner's value
#define DPP_ROR4   0x124
#define DPP_ROR8   0x128
template<int CTRL>
__device__ __forceinline__ float dppf(float x) {
    int r = __builtin_amdgcn_update_dpp(0, __builtin_bit_cast(int, x), CTRL, 0xF, 0xF, true);
    return __builtin_bit_cast(float, r);
}

__device__ __forceinline__ void loadx4(float (&dst)[4], const float* __restrict__ x_r,
                                       const float* __restrict__ x_t,
                                       size_t xrb, size_t xtb, int l) {
#pragma unroll
    for (int u = 0; u < 4; ++u) {
        int v = l + 16 * u;
        dst[u] = (v < 47) ? x_r[xrb + v] : ((v < 49) ? x_t[xtb + (v - 47)] : 0.0f);
    }
}

__device__ __forceinline__ void unpack12(f2 (&in)[24], const float4* __restrict__ r4) {
#pragma unroll
    for (int u = 0; u < 12; ++u) {
        float4 v = r4[u];
        in[2 * u]     = f2{v.x, v.y};
        in[2 * u + 1] = f2{v.z, v.w};
    }
}

// 48 f16 (24 h2) as 6 ds_read_b128
__device__ __forceinline__ void unpackh(h2 (&in)[24], const h2* __restrict__ row) {
    const float4* q = (const float4*)row;
#pragma unroll
    for (int k = 0; k < 6; ++k) {
        float4 v = q[k];
        in[4 * k + 0] = __builtin_bit_cast(h2, v.x);
        in[4 * k + 1] = __builtin_bit_cast(h2, v.y);
        in[4 * k + 2] = __builtin_bit_cast(h2, v.z);
        in[4 * k + 3] = __builtin_bit_cast(h2, v.w);
    }
}

__device__ __forceinline__ float4 dot4h(const h2 (&in)[24], const h2 (&w)[4][24], float4 init) {
    float a0 = init.x, a1 = init.y, a2 = init.z, a3 = init.w;
#pragma unroll
    for (int u = 0; u < 24; ++u) {
        a0 = FDOT2(w[0][u], in[u], a0);
        a1 = FDOT2(w[1][u], in[u], a1);
        a2 = FDOT2(w[2][u], in[u], a2);
        a3 = FDOT2(w[3][u], in[u], a3);
    }
    return float4{a0, a1, a2, a3};
}

// load a 47-col f32 weight row as 24 packed-f16 pairs (pad last to 0)
__device__ __forceinline__ void loadw47h(h2 (&w)[24], const float* __restrict__ src) {
#pragma unroll
    for (int u = 0; u < 23; ++u)
        w[u] = h2{(_Float16)src[2 * u], (_Float16)src[2 * u + 1]};
    w[23] = h2{(_Float16)src[46], (_Float16)0.0f};
}

__global__ __launch_bounds__(320) void adrnn_fused(
    const float* __restrict__ x_r, const float* __restrict__ x_t,
    const float* __restrict__ rWih0, const float* __restrict__ rWhh0,
    const float* __restrict__ rbih0, const float* __restrict__ rbhh0,
    const float* __restrict__ rWih1, const float* __restrict__ rWhh1,
    const float* __restrict__ rbih1, const float* __restrict__ rbhh1,
    const float* __restrict__ tWih0, const float* __restrict__ tWhh0,
    const float* __restrict__ tbih0, const float* __restrict__ tbhh0,
    const float* __restrict__ tWih1, const float* __restrict__ tWhh1,
    const float* __restrict__ tbih1, const float* __restrict__ tbhh1,
    float* __restrict__ r_out, float* __restrict__ t_out)
{
    // tring: f32, staged x + h1 for the t-RNN. h0f16/h1f16: packed-f16 recurrent
    // rings (halve the in-chain ds_read count). pA/pB: f32 float4 per unit,
    // XOR-swizzled slot (j^(j>>3)) to kill the 16B-stride 8-way bank conflict.
    __shared__ __align__(16) float tring[64][112]; // [x 0..48 | pad | h1 64..110 | pad]
    __shared__ __align__(16) h2 h0f16[16][32];     // h0(s), 24 h2 used, row 128B
    __shared__ __align__(16) h2 h1f16[16][32];     // h1(s) for HB recurrence
    __shared__ __align__(16) float pAring[16][192];
    __shared__ __align__(16) float pBring[16][192];

    const int tid = threadIdx.x;
    const int wid = tid >> 6;
    const int l   = tid & 63;
    const int j   = l;
    const int b = blockIdx.x;
    const size_t xr_base = (size_t)b * T_STEPS * 47;
    const size_t xt_base = (size_t)b * T_STEPS * 2;

    if (tid < 256) {
        for (int k = tid; k < 64 * 48; k += 256) tring[k / 48][64 + (k % 48)] = 0.0f;
        for (int k = tid; k < 16 * 32; k += 256) {
            h0f16[k >> 5][k & 31] = h2{(_Float16)0.0f, (_Float16)0.0f};
            h1f16[k >> 5][k & 31] = h2{(_Float16)0.0f, (_Float16)0.0f};
        }
    }

    if (wid == 0) {
        // ===== XA (lag 0): pA(i) = Wih0*x(i)+b0, f32 path =====
        f2 w[4][24]; float w48[4]; float4 bias = {0, 0, 0, 0};
#pragma unroll
        for (int g = 0; g < 4; ++g) { w48[g] = 0.f;
#pragma unroll
            for (int u = 0; u < 24; ++u) w[g][u] = f2{0.f, 0.f}; }
        if (j < 47) {
            float bb[4];
#pragma unroll
            for (int g = 0; g < 4; ++g) {
                const int row = g * 47 + j;
#pragma unroll
                for (int u = 0; u < 24; ++u)
                    w[g][u] = f2{rWih0[row * 49 + 2 * u], rWih0[row * 49 + 2 * u + 1]};
                w48[g] = rWih0[row * 49 + 48];
                bb[g] = rbih0[row] + rbhh0[row];
            }
            bias = {bb[0], bb[1], bb[2], bb[3]};
        }
        const int jsw4 = (j ^ (j >> 3)) * 4;
        __syncthreads();
        for (int i = 0; i < TOTAL; ++i) {
            if (i < T_STEPS && j < 47) {
                f2 in[24];
                unpack12(in, (const float4*)&tring[i & 63][0]);
                float x48 = tring[i & 63][48];
                f2 a0 = f2{bias.x, 0.f}, a1 = f2{bias.y, 0.f}, a2 = f2{bias.z, 0.f}, a3 = f2{bias.w, 0.f};
#pragma unroll
                for (int u = 0; u < 24; ++u) {
                    a0 = __builtin_elementwise_fma(w[0][u], in[u], a0);
                    a1 = __builtin_elementwise_fma(w[1][u], in[u], a1);
                    a2 = __builtin_elementwise_fma(w[2][u], in[u], a2);
                    a3 = __builtin_elementwise_fma(w[3][u], in[u], a3);
                }
                float4 out;
                out.x = fmaf(w48[0], x48, a0.x + a0.y);
                out.y = fmaf(w48[1], x48, a1.x + a1.y);
                out.z = fmaf(w48[2], x48, a2.x + a2.y);
                out.w = fmaf(w48[3], x48, a3.x + a3.y);
                *(float4*)&pAring[i & 15][jsw4] = out;
            }
            if ((i & 7) == 7) LDS_BARRIER();
        }
    } else if (wid == 1) {
        // ===== HA (lag 8): h0(s) = cell(pA(s) + Whh0*h0(s-1)), f16 dots =====
        h2 w[4][24];
#pragma unroll
        for (int g = 0; g < 4; ++g)
#pragma unroll
            for (int u = 0; u < 24; ++u) w[g][u] = h2{(_Float16)0.0f, (_Float16)0.0f};
        if (j < 47) {
#pragma unroll
            for (int g = 0; g < 4; ++g) loadw47h(w[g], &rWhh0[(g * 47 + j) * 47]);
        }
        const int jsw4 = (j ^ (j >> 3)) * 4;
        float c0 = 0.f;
        __syncthreads();
        for (int i = 0; i < TOTAL; ++i) {
            const int s = i - 8;
            float hv = 0.0f;
            if (s >= 0 && s < T_STEPS && j < 47) {
                float4 pa = *(const float4*)&pAring[s & 15][jsw4];
                h2 in[24];
                unpackh(in, &h0f16[(s - 1) & 15][0]);
                float4 pre = dot4h(in, w, pa);
                float iv = sig_f(pre.x), fv = sig_f(pre.y);
                float gv = tanh_f(pre.z), ov = sig_f(pre.w);
                c0 = fmaf(fv, c0, iv * gv);
                hv = ov * tanh_f(c0);
            }
            float hn = dppf<DPP_PAIR>(hv);     // even lane gets odd partner's h
            if (s >= 0 && s < T_STEPS && j < 47 && !(j & 1)) {
                h0f16[s & 15][j >> 1] = __builtin_bit_cast(h2, __builtin_amdgcn_cvt_pkrtz(hv, hn));
            }
            if ((i & 7) == 7) LDS_BARRIER();
        }
    } else if (wid == 2) {
        // ===== XB (lag 16): pB(s) = Wih1*h0(s)+b1, f16 dots =====
        h2 w[4][24]; float4 bias = {0, 0, 0, 0};
#pragma unroll
        for (int g = 0; g < 4; ++g)
#pragma unroll
            for (int u = 0; u < 24; ++u) w[g][u] = h2{(_Float16)0.0f, (_Float16)0.0f};
        if (j < 47) {
            float bb[4];
#pragma unroll
            for (int g = 0; g < 4; ++g) {
                loadw47h(w[g], &rWih1[(g * 47 + j) * 47]);
                bb[g] = rbih1[g * 47 + j] + rbhh1[g * 47 + j];
            }
            bias = {bb[0], bb[1], bb[2], bb[3]};
        }
        const int jsw4 = (j ^ (j >> 3)) * 4;
        __syncthreads();
        for (int i = 0; i < TOTAL; ++i) {
            const int s = i - 16;
            if (s >= 0 && s < T_STEPS && j < 47) {
                h2 in[24];
                unpackh(in, &h0f16[s & 15][0]);
                float4 pre = dot4h(in, w, bias);
                *(float4*)&pBring[s & 15][jsw4] = pre;
            }
            if ((i & 7) == 7) LDS_BARRIER();
        }
    } else if (wid == 3) {
        // ===== HB (lag 24): h1(s) = cell(pB(s) + Whh1*h1(s-1)), f16 dots =====
        h2 w[4][24];
#pragma unroll
        for (int g = 0; g < 4; ++g)
#pragma unroll
            for (int u = 0; u < 24; ++u) w[g][u] = h2{(_Float16)0.0f, (_Float16)0.0f};
        if (j < 47) {
#pragma unroll
            for (int g = 0; g < 4; ++g) loadw47h(w[g], &rWhh1[(g * 47 + j) * 47]);
        }
        const int jsw4 = (j ^ (j >> 3)) * 4;
        float c1 = 0.f;
        __syncthreads();
        for (int i = 0; i < TOTAL; ++i) {
            const int s = i - 24;
            float hv = 0.0f;
            if (s >= 0 && s < T_STEPS && j < 47) {
                float4 pb = *(const float4*)&pBring[s & 15][jsw4];
                h2 in[24];
                unpackh(in, &h1f16[(s - 1) & 15][0]);
                float4 pre = dot4h(in, w, pb);
                float iv = sig_f(pre.x), fv = sig_f(pre.y);
                float gv = tanh_f(pre.z), ov = sig_f(pre.w);
                c1 = fmaf(fv, c1, iv * gv);
                hv = ov * tanh_f(c1);
                tring[s & 63][64 + j] = hv;    // f32 for TT
                r_out[((size_t)b * T_STEPS + s) * 47 + j] = hv;
            }
            float hn = dppf<DPP_PAIR>(hv);
            if (s >= 0 && s < T_STEPS && j < 47 && !(j & 1)) {
                h1f16[s & 15][j >> 1] = __builtin_bit_cast(h2, __builtin_amdgcn_cvt_pkrtz(hv, hn));
            }
            if ((i & 7) == 7) LDS_BARRIER();
        }
    } else {
        // ===== TT (lag 32): t-RNN + x staging (8 ahead), f32 path =====
        const int u  = (l >> 2) & 1;
        const int g  = l & 3;
        const int hf = (l >> 3) & 1;
        const int R0 = g * 2 + u;
        f2 wt[24]; float wx48;
        if (hf == 0) {
            wx48 = 0.f;
#pragma unroll
            for (int k = 0; k < 24; ++k)
                wt[k] = f2{tWih0[R0 * 96 + 2 * k], tWih0[R0 * 96 + 2 * k + 1]};
        } else {
            wx48 = tWih0[R0 * 96 + 48];
#pragma unroll
            for (int k = 0; k < 23; ++k)
                wt[k] = f2{tWih0[R0 * 96 + 49 + 2 * k], tWih0[R0 * 96 + 49 + 2 * k + 1]};
            wt[23] = f2{tWih0[R0 * 96 + 95], 0.f};
        }
        const float bT0 = tbih0[R0] + tbhh0[R0];
        const float wh00 = tWhh0[R0 * 2 + 0], wh01 = tWhh0[R0 * 2 + 1];
        const float wi10 = tWih1[R0 * 2 + 0], wi11 = tWih1[R0 * 2 + 1];
        const float wh10 = tWhh1[R0 * 2 + 0], wh11 = tWhh1[R0 * 2 + 1];
        const float bT1 = tbih1[R0] + tbhh1[R0];
        const bool isg = (g == 2);
        const float zm = isg ? 2.f : 1.f, sm = isg ? 2.f : 1.f, sa = isg ? -1.f : 0.f;
        float ht00 = 0.f, ht01 = 0.f, ct0u = 0.f;
        float ht10 = 0.f, ht11 = 0.f, ct1u = 0.f;

        float xa[4] = {0,0,0,0}, xb[4] = {0,0,0,0}, xc[4] = {0,0,0,0};
        if (l < 16) {
            for (int t = 0; t < 8; ++t) {
                float xv[4];
                loadx4(xv, x_r, x_t, xr_base + (size_t)t * 47, xt_base + (size_t)t * 2, l);
#pragma unroll
                for (int uu = 0; uu < 4; ++uu) {
                    int v = l + 16 * uu;
                    if (v < 49) tring[t][v] = xv[uu];
                }
            }
            loadx4(xa, x_r, x_t, xr_base + (size_t)8 * 47,  xt_base + (size_t)8 * 2,  l);
            loadx4(xb, x_r, x_t, xr_base + (size_t)9 * 47,  xt_base + (size_t)9 * 2,  l);
            loadx4(xc, x_r, x_t, xr_base + (size_t)10 * 47, xt_base + (size_t)10 * 2, l);
        }
        __syncthreads();

        for (int i = 0; i < TOTAL; ++i) {
            if (l < 16) {
                const int tw = i + 8;
                if (tw < T_STEPS) {
#pragma unroll
                    for (int uu = 0; uu < 4; ++uu) {
                        int v = l + 16 * uu;
                        if (v < 49) tring[tw & 63][v] = xa[uu];
                    }
                }
#pragma unroll
                for (int uu = 0; uu < 4; ++uu) { xa[uu] = xb[uu]; xb[uu] = xc[uu]; }
                int tl = i + 11;
                if (tl > T_STEPS - 1) tl = T_STEPS - 1;
                loadx4(xc, x_r, x_t, xr_base + (size_t)tl * 47, xt_base + (size_t)tl * 2, l);
            }
            const int s = i - 32;
            if (s >= 0 && s < T_STEPS) {
                f2 in[24];
                unpack12(in, (const float4*)&tring[s & 63][hf ? 64 : 0]);
                float x48 = tring[s & 63][48];
                f2 av = {0, 0}, bv = {0, 0};
#pragma unroll
                for (int k = 0; k < 12; ++k) {
                    av = __builtin_elementwise_fma(wt[2 * k],     in[2 * k],     av);
                    bv = __builtin_elementwise_fma(wt[2 * k + 1], in[2 * k + 1], bv);
                }
                f2 sv = av + bv;
                float part = fmaf(wx48, x48, sv.x + sv.y);
                float pre0 = part + dppf<DPP_ROR8>(part);
                pre0 += bT0 + wh00 * ht00 + wh01 * ht01;
                float a0 = gate_act(pre0, zm, sm, sa);
                float i0 = dppf<DPP_BCAST0>(a0);
                float f0 = dppf<DPP_BCAST1>(a0);
                float g0 = dppf<DPP_BCAST2>(a0);
                float o0 = dppf<DPP_BCAST3>(a0);
                ct0u = fmaf(f0, ct0u, i0 * g0);
                float htu = o0 * tanh_f(ct0u);
                float hto = dppf<DPP_ROR4>(htu);
                ht00 = (u == 0) ? htu : hto;
                ht01 = (u == 0) ? hto : htu;
                float pre1 = bT1 + wi10 * ht00 + wi11 * ht01 + wh10 * ht10 + wh11 * ht11;
                float a1 = gate_act(pre1, zm, sm, sa);
                float ji = dppf<DPP_BCAST0>(a1);
                float jf = dppf<DPP_BCAST1>(a1);
                float jg = dppf<DPP_BCAST2>(a1);
                float jo = dppf<DPP_BCAST3>(a1);
                ct1u = fmaf(jf, ct1u, ji * jg);
                float h1u = jo * tanh_f(ct1u);
                float h1o = dppf<DPP_ROR4>(h1u);
                ht10 = (u == 0) ? h1u : h1o;
                ht11 = (u == 0) ? h1o : h1u;
                if (l == 0) {
                    float2 tv = {ht10, ht11};
                    *reinterpret_cast<float2*>(&t_out[((size_t)b * T_STEPS + s) * 2]) = tv;
                }
            }
            if ((i & 7) == 7) LDS_BARRIER();
        }
    }
}

extern "C" void kernel_launch(void* const* d_in, const int* in_sizes, int n_in,
                              void* d_out, int out_size, void* d_ws, size_t ws_size,
                              hipStream_t stream) {
    const float* x_r   = (const float*)d_in[0];
    const float* x_t   = (const float*)d_in[1];
    const float* rWih0 = (const float*)d_in[2];
    const float* rWhh0 = (const float*)d_in[3];
    const float* rbih0 = (const float*)d_in[4];
    const float* rbhh0 = (const float*)d_in[5];
    const float* rWih1 = (const float*)d_in[6];
    const float* rWhh1 = (const float*)d_in[7];
    const float* rbih1 = (const float*)d_in[8];
    const float* rbhh1 = (const float*)d_in[9];
    const float* tWih0 = (const float*)d_in[10];
    const float* tWhh0 = (const float*)d_in[11];
    const float* tbih0 = (const float*)d_in[12];
    const float* tbhh0 = (const float*)d_in[13];
    const float* tWih1 = (const float*)d_in[14];
    const float* tWhh1 = (const float*)d_in[15];
    const float* tbih1 = (const float*)d_in[16];
    const float* tbhh1 = (const float*)d_in[17];

    float* r_out = (float*)d_out;
    float* t_out = r_out + (size_t)256 * T_STEPS * 47;

    hipLaunchKernelGGL(adrnn_fused, dim3(256), dim3(320), 0, stream,
                       x_r, x_t, rWih0, rWhh0, rbih0, rbhh0, rWih1, rWhh1, rbih1, rbhh1,
                       tWih0, tWhh0, tbih0, tbhh0, tWih1, tWhh1, tbih1, tbhh1,
                       r_out, t_out);
}